// Round 1
// baseline (605.255 us; speedup 1.0000x reference)
//
#include <hip/hip_runtime.h>
#include <hip/hip_bf16.h>

#define CIN 128
#define COUT 512
#define NEG_SLOPE 0.1f

typedef __bf16 bf16x8 __attribute__((ext_vector_type(8)));
typedef float f32x4 __attribute__((ext_vector_type(4)));

static __device__ __forceinline__ unsigned short f2bf(float f) {
  unsigned int u = __builtin_bit_cast(unsigned int, f);
  unsigned int lsb = (u >> 16) & 1u;
  u += 0x7fffu + lsb;  // round-to-nearest-even
  return (unsigned short)(u >> 16);
}

// ---- Edge dtype probe: int64 stored data has every odd int32 word == 0 ----
__global__ void detect_kernel(const int* __restrict__ raw, int* __restrict__ flag, int E) {
  __shared__ int any_nonzero;
  int tid = threadIdx.x;  // 64 threads
  if (tid == 0) any_nonzero = 0;
  __syncthreads();
  int v1 = raw[2 * tid + 1];                  // odd words near start
  int v2 = raw[2 * (E / 2) + 2 * tid + 1];    // odd words near row-1 start
  if (v1 != 0 || v2 != 0) atomicOr(&any_nonzero, 1);
  __syncthreads();
  if (tid == 0) *flag = any_nonzero ? 0 : 1;  // 1 => data is int64
}

__global__ void decode_kernel(const int* __restrict__ raw, const int* __restrict__ flag,
                              int* __restrict__ srcA, int* __restrict__ dstA, int E, int N) {
  int e = blockIdx.x * blockDim.x + threadIdx.x;
  if (e >= E) return;
  int is64 = *flag;
  int s, d;
  if (is64) {
    s = raw[2 * e];            // low word of element e (row 0)
    d = raw[2 * (E + e)];      // low word of element E+e (row 1)
  } else {
    s = raw[e];
    d = raw[E + e];
  }
  if ((unsigned)s >= (unsigned)N) s = 0;  // safety clamp (should not trigger)
  if ((unsigned)d >= (unsigned)N) d = 0;
  srcA[e] = s;
  dstA[e] = d;
}

__global__ void count_kernel(const int* __restrict__ dstA, int* __restrict__ cnt, int E) {
  int e = blockIdx.x * blockDim.x + threadIdx.x;
  if (e < E) atomicAdd(&cnt[dstA[e]], 1);
}

__global__ void dinv_kernel(const int* __restrict__ cnt, float* __restrict__ dinv, int N) {
  int i = blockIdx.x * blockDim.x + threadIdx.x;
  if (i < N) dinv[i] = 1.0f / sqrtf((float)(cnt[i] + 1));  // +1 = self-loop
}

// Single-block exclusive scan over N counts -> rowptr (and cursor copy).
__global__ void scan_kernel(const int* __restrict__ cnt, int* __restrict__ rowptr,
                            int* __restrict__ cursor, int N) {
  __shared__ int buf[256];
  __shared__ int carry_s;
  int tid = threadIdx.x;
  if (tid == 0) carry_s = 0;
  __syncthreads();
  for (int base = 0; base < N; base += 256) {
    int i = base + tid;
    int v = (i < N) ? cnt[i] : 0;
    buf[tid] = v;
    __syncthreads();
    for (int off = 1; off < 256; off <<= 1) {
      int t = (tid >= off) ? buf[tid - off] : 0;
      __syncthreads();
      buf[tid] += t;
      __syncthreads();
    }
    int incl = buf[tid];
    int carry = carry_s;
    int excl = carry + incl - v;
    if (i < N) { rowptr[i] = excl; cursor[i] = excl; }
    int total = buf[255];
    __syncthreads();
    if (tid == 0) carry_s = carry + total;
    __syncthreads();
  }
}

__global__ void scatter_kernel(const int* __restrict__ srcA, const int* __restrict__ dstA,
                               int* __restrict__ cursor, int* __restrict__ col, int E) {
  int e = blockIdx.x * blockDim.x + threadIdx.x;
  if (e < E) {
    int pos = atomicAdd(&cursor[dstA[e]], 1);
    col[pos] = srcA[e];
  }
}

// One wave per node: gather neighbors (CSR by dst), accumulate 128 channels
// as float2 per lane. OUT_BF16 selects fp32 (hop 1) vs bf16 (hop 2) output.
template <bool OUT_BF16>
__global__ void hop_kernel(const float* __restrict__ X, const float* __restrict__ dinv,
                           const int* __restrict__ rowptr, const int* __restrict__ cnt,
                           const int* __restrict__ col, void* __restrict__ Yv, int N) {
  int i = blockIdx.x;
  int lane = threadIdx.x;  // 0..63
  float di = dinv[i];
  int beg = rowptr[i];
  int num = cnt[i];
  const float2* Xi = (const float2*)X + (size_t)i * 64;
  float2 xv = Xi[lane];
  float s = di * di;
  float ax = s * xv.x;
  float ay = s * xv.y;
  int j = (num > 0) ? col[beg] : 0;
  for (int k = 0; k < num; ++k) {
    int jn = (k + 1 < num) ? col[beg + k + 1] : 0;  // prefetch next index
    float nrm = dinv[j] * di;
    float2 v = ((const float2*)X + (size_t)j * 64)[lane];
    ax += nrm * v.x;
    ay += nrm * v.y;
    j = jn;
  }
  if constexpr (OUT_BF16) {
    ushort2* Y = (ushort2*)Yv + (size_t)i * 64;
    ushort2 o; o.x = f2bf(ax); o.y = f2bf(ay);
    Y[lane] = o;
  } else {
    float2* Y = (float2*)Yv + (size_t)i * 64;
    float2 o; o.x = ax; o.y = ay;
    Y[lane] = o;
  }
}

__global__ void wconv_kernel(const float* __restrict__ W, unsigned short* __restrict__ Wbf, int n) {
  int i = blockIdx.x * blockDim.x + threadIdx.x;
  if (i < n) Wbf[i] = f2bf(W[i]);
}

// y = h2 @ W^T + b, LeakyReLU. A=h2 [M,128] bf16, B[k][n]=W[n][k] (Wbf rows).
// Block = 4 waves; wave w covers n-tile (by*64 + w*16), all 4 m-subtiles of
// the block's 64 rows. mfma_f32_16x16x32_bf16, 4 k-steps (K=128).
__global__ __launch_bounds__(256) void gemm_kernel(
    const unsigned short* __restrict__ Abf, const unsigned short* __restrict__ Wbf,
    const float* __restrict__ bias, float* __restrict__ out, int M) {
  int wave = threadIdx.x >> 6;
  int lane = threadIdx.x & 63;
  int quad = lane >> 4;
  int l16 = lane & 15;
  int mbase = blockIdx.x * 64;
  int n0 = blockIdx.y * 64 + wave * 16;

  f32x4 acc[4] = {};
  bool valid[4];
#pragma unroll
  for (int t = 0; t < 4; ++t) valid[t] = (mbase + t * 16) < M;  // M % 16 == 0

  const bf16x8* Wrow = (const bf16x8*)(Wbf + (size_t)(n0 + l16) * CIN);
#pragma unroll
  for (int kk = 0; kk < 4; ++kk) {
    bf16x8 bfrag = Wrow[kk * 4 + quad];  // B[k=kk*32+quad*8+j][n=l16]
#pragma unroll
    for (int t = 0; t < 4; ++t) {
      if (!valid[t]) continue;
      const bf16x8* Arow = (const bf16x8*)(Abf + (size_t)(mbase + t * 16 + l16) * CIN);
      bf16x8 afrag = Arow[kk * 4 + quad];  // A[m=l16][k=kk*32+quad*8+j]
      acc[t] = __builtin_amdgcn_mfma_f32_16x16x32_bf16(afrag, bfrag, acc[t], 0, 0, 0);
    }
  }

  float bv = bias[n0 + l16];
#pragma unroll
  for (int t = 0; t < 4; ++t) {
    if (!valid[t]) continue;
#pragma unroll
    for (int r = 0; r < 4; ++r) {
      int row = mbase + t * 16 + quad * 4 + r;  // C/D: row=quad*4+r, col=l16
      float y = acc[t][r] + bv;
      y = (y >= 0.f) ? y : NEG_SLOPE * y;
      out[(size_t)row * COUT + n0 + l16] = y;
    }
  }
}

static inline size_t align_up(size_t v, size_t a) { return (v + a - 1) & ~(a - 1); }

extern "C" void kernel_launch(void* const* d_in, const int* in_sizes, int n_in,
                              void* d_out, int out_size, void* d_ws, size_t ws_size,
                              hipStream_t stream) {
  const float* x = (const float*)d_in[0];
  const int* edge_raw = (const int*)d_in[1];
  const float* W = (const float*)d_in[2];
  const float* b = (const float*)d_in[3];
  float* out = (float*)d_out;

  const int N = in_sizes[0] / CIN;
  const int E = in_sizes[1] / 2;

  // Workspace layout
  char* w = (char*)d_ws;
  int* flag = (int*)w;            w += align_up(sizeof(int), 256);
  int* cnt = (int*)w;             w += align_up((size_t)N * 4, 256);
  int* rowptr = (int*)w;          w += align_up((size_t)N * 4, 256);
  int* cursor = (int*)w;          w += align_up((size_t)N * 4, 256);
  float* dinv = (float*)w;        w += align_up((size_t)N * 4, 256);
  int* srcA = (int*)w;            w += align_up((size_t)E * 4, 256);
  int* dstA = (int*)w;            w += align_up((size_t)E * 4, 256);
  int* col = (int*)w;             w += align_up((size_t)E * 4, 256);
  unsigned short* h2bf = (unsigned short*)w;  w += align_up((size_t)N * CIN * 2, 256);
  unsigned short* Wbf = (unsigned short*)w;   w += align_up((size_t)COUT * CIN * 2, 256);

  float* h1 = out;  // d_out as fp32 scratch for hop-1 result (N*128 <= out_size)

  hipMemsetAsync(cnt, 0, (size_t)N * sizeof(int), stream);

  detect_kernel<<<1, 64, 0, stream>>>(edge_raw, flag, E);
  decode_kernel<<<(E + 255) / 256, 256, 0, stream>>>(edge_raw, flag, srcA, dstA, E, N);
  count_kernel<<<(E + 255) / 256, 256, 0, stream>>>(dstA, cnt, E);
  dinv_kernel<<<(N + 255) / 256, 256, 0, stream>>>(cnt, dinv, N);
  scan_kernel<<<1, 256, 0, stream>>>(cnt, rowptr, cursor, N);
  scatter_kernel<<<(E + 255) / 256, 256, 0, stream>>>(srcA, dstA, cursor, col, E);

  hop_kernel<false><<<N, 64, 0, stream>>>(x, dinv, rowptr, cnt, col, (void*)h1, N);
  hop_kernel<true><<<N, 64, 0, stream>>>(h1, dinv, rowptr, cnt, col, (void*)h2bf, N);

  wconv_kernel<<<(COUT * CIN + 255) / 256, 256, 0, stream>>>(W, Wbf, COUT * CIN);

  dim3 ggrid((N + 63) / 64, COUT / 64);
  gemm_kernel<<<ggrid, 256, 0, stream>>>(h2bf, Wbf, b, out, N);
}

// Round 2
// 403.974 us; speedup vs baseline: 1.4983x; 1.4983x over previous
//
#include <hip/hip_runtime.h>
#include <hip/hip_bf16.h>

#define CIN 128
#define COUT 512
#define NEG_SLOPE 0.1f

typedef __bf16 bf16x8 __attribute__((ext_vector_type(8)));
typedef float f32x4 __attribute__((ext_vector_type(4)));

static __device__ __forceinline__ unsigned short f2bf(float f) {
  unsigned int u = __builtin_bit_cast(unsigned int, f);
  unsigned int lsb = (u >> 16) & 1u;
  u += 0x7fffu + lsb;  // round-to-nearest-even
  return (unsigned short)(u >> 16);
}

// ---- Edge dtype probe: int64 stored data has every odd int32 word == 0 ----
__global__ void detect_kernel(const int* __restrict__ raw, int* __restrict__ flag, int E) {
  __shared__ int any_nonzero;
  int tid = threadIdx.x;  // 64 threads
  if (tid == 0) any_nonzero = 0;
  __syncthreads();
  int v1 = raw[2 * tid + 1];                  // odd words near start
  int v2 = raw[2 * (E / 2) + 2 * tid + 1];    // odd words near row-1 start
  if (v1 != 0 || v2 != 0) atomicOr(&any_nonzero, 1);
  __syncthreads();
  if (tid == 0) *flag = any_nonzero ? 0 : 1;  // 1 => data is int64
}

// Fused decode + degree count (saves one pass over E).
__global__ void decode_count_kernel(const int* __restrict__ raw, const int* __restrict__ flag,
                                    int* __restrict__ srcA, int* __restrict__ dstA,
                                    int* __restrict__ cnt, int E, int N) {
  int e = blockIdx.x * blockDim.x + threadIdx.x;
  if (e >= E) return;
  int is64 = *flag;
  int s, d;
  if (is64) {
    s = raw[2 * e];            // low word of element e (row 0)
    d = raw[2 * (E + e)];      // low word of element E+e (row 1)
  } else {
    s = raw[e];
    d = raw[E + e];
  }
  if ((unsigned)s >= (unsigned)N) s = 0;  // safety clamp (should not trigger)
  if ((unsigned)d >= (unsigned)N) d = 0;
  srcA[e] = s;
  dstA[e] = d;
  atomicAdd(&cnt[d], 1);
}

__global__ void dinv_kernel(const int* __restrict__ cnt, float* __restrict__ dinv, int N) {
  int i = blockIdx.x * blockDim.x + threadIdx.x;
  if (i < N) dinv[i] = 1.0f / sqrtf((float)(cnt[i] + 1));  // +1 = self-loop
}

// ---- Hierarchical device-wide exclusive scan (replaces 216us serial scan) ----
// Phase 1: per-block (1024 elems, 4/thread) exclusive scan -> rowptr; block sums -> bsum
__global__ __launch_bounds__(256) void scan1_kernel(const int* __restrict__ cnt,
                                                    int* __restrict__ rowptr,
                                                    int* __restrict__ bsum, int N) {
  __shared__ int buf[256];
  int tid = threadIdx.x;
  int base = blockIdx.x * 1024 + tid * 4;
  int v[4];
  int tot = 0;
#pragma unroll
  for (int k = 0; k < 4; ++k) {
    int i = base + k;
    v[k] = (i < N) ? cnt[i] : 0;
    tot += v[k];
  }
  buf[tid] = tot;
  __syncthreads();
  for (int off = 1; off < 256; off <<= 1) {
    int t = (tid >= off) ? buf[tid - off] : 0;
    __syncthreads();
    buf[tid] += t;
    __syncthreads();
  }
  int run = buf[tid] - tot;  // exclusive prefix of this thread within block
  if (tid == 255) bsum[blockIdx.x] = buf[255];
#pragma unroll
  for (int k = 0; k < 4; ++k) {
    int i = base + k;
    if (i < N) rowptr[i] = run;
    run += v[k];
  }
}

// Phase 2: exclusive scan of the (<=256) block sums, in place, one block.
__global__ void scan2_kernel(int* __restrict__ bsum, int nb) {
  __shared__ int buf[256];
  int tid = threadIdx.x;
  int v = (tid < nb) ? bsum[tid] : 0;
  buf[tid] = v;
  __syncthreads();
  for (int off = 1; off < 256; off <<= 1) {
    int t = (tid >= off) ? buf[tid - off] : 0;
    __syncthreads();
    buf[tid] += t;
    __syncthreads();
  }
  if (tid < nb) bsum[tid] = buf[tid] - v;
}

// Phase 3: add block offset; emit final rowptr and cursor copy.
__global__ __launch_bounds__(256) void scan3_kernel(int* __restrict__ rowptr,
                                                    const int* __restrict__ bsum,
                                                    int* __restrict__ cursor, int N) {
  int base = blockIdx.x * 1024 + threadIdx.x * 4;
  int off = bsum[blockIdx.x];
#pragma unroll
  for (int k = 0; k < 4; ++k) {
    int i = base + k;
    if (i < N) {
      int r = rowptr[i] + off;
      rowptr[i] = r;
      cursor[i] = r;
    }
  }
}

__global__ void scatter_kernel(const int* __restrict__ srcA, const int* __restrict__ dstA,
                               int* __restrict__ cursor, int* __restrict__ col, int E) {
  int e = blockIdx.x * blockDim.x + threadIdx.x;
  if (e < E) {
    int pos = atomicAdd(&cursor[dstA[e]], 1);
    col[pos] = srcA[e];
  }
}

// One wave per node: gather neighbors (CSR by dst), accumulate 128 channels
// as float2 per lane. OUT_BF16 selects fp32 (hop 1) vs bf16 (hop 2) output.
template <bool OUT_BF16>
__global__ void hop_kernel(const float* __restrict__ X, const float* __restrict__ dinv,
                           const int* __restrict__ rowptr, const int* __restrict__ cnt,
                           const int* __restrict__ col, void* __restrict__ Yv, int N) {
  int i = blockIdx.x;
  int lane = threadIdx.x;  // 0..63
  float di = dinv[i];
  int beg = rowptr[i];
  int num = cnt[i];
  const float2* Xi = (const float2*)X + (size_t)i * 64;
  float2 xv = Xi[lane];
  float s = di * di;
  float ax = s * xv.x;
  float ay = s * xv.y;
  int j = (num > 0) ? col[beg] : 0;
  for (int k = 0; k < num; ++k) {
    int jn = (k + 1 < num) ? col[beg + k + 1] : 0;  // prefetch next index
    float nrm = dinv[j] * di;
    float2 v = ((const float2*)X + (size_t)j * 64)[lane];
    ax += nrm * v.x;
    ay += nrm * v.y;
    j = jn;
  }
  if constexpr (OUT_BF16) {
    ushort2* Y = (ushort2*)Yv + (size_t)i * 64;
    ushort2 o; o.x = f2bf(ax); o.y = f2bf(ay);
    Y[lane] = o;
  } else {
    float2* Y = (float2*)Yv + (size_t)i * 64;
    float2 o; o.x = ax; o.y = ay;
    Y[lane] = o;
  }
}

__global__ void wconv_kernel(const float* __restrict__ W, unsigned short* __restrict__ Wbf, int n) {
  int i = blockIdx.x * blockDim.x + threadIdx.x;
  if (i < n) Wbf[i] = f2bf(W[i]);
}

// y = h2 @ W^T + b, LeakyReLU. A=h2 [M,128] bf16, B[k][n]=W[n][k] (Wbf rows).
__global__ __launch_bounds__(256) void gemm_kernel(
    const unsigned short* __restrict__ Abf, const unsigned short* __restrict__ Wbf,
    const float* __restrict__ bias, float* __restrict__ out, int M) {
  int wave = threadIdx.x >> 6;
  int lane = threadIdx.x & 63;
  int quad = lane >> 4;
  int l16 = lane & 15;
  int mbase = blockIdx.x * 64;
  int n0 = blockIdx.y * 64 + wave * 16;

  f32x4 acc[4] = {};
  bool valid[4];
#pragma unroll
  for (int t = 0; t < 4; ++t) valid[t] = (mbase + t * 16) < M;  // M % 16 == 0

  const bf16x8* Wrow = (const bf16x8*)(Wbf + (size_t)(n0 + l16) * CIN);
#pragma unroll
  for (int kk = 0; kk < 4; ++kk) {
    bf16x8 bfrag = Wrow[kk * 4 + quad];  // B[k=kk*32+quad*8+j][n=l16]
#pragma unroll
    for (int t = 0; t < 4; ++t) {
      if (!valid[t]) continue;
      const bf16x8* Arow = (const bf16x8*)(Abf + (size_t)(mbase + t * 16 + l16) * CIN);
      bf16x8 afrag = Arow[kk * 4 + quad];  // A[m=l16][k=kk*32+quad*8+j]
      acc[t] = __builtin_amdgcn_mfma_f32_16x16x32_bf16(afrag, bfrag, acc[t], 0, 0, 0);
    }
  }

  float bv = bias[n0 + l16];
#pragma unroll
  for (int t = 0; t < 4; ++t) {
    if (!valid[t]) continue;
#pragma unroll
    for (int r = 0; r < 4; ++r) {
      int row = mbase + t * 16 + quad * 4 + r;  // C/D: row=quad*4+r, col=l16
      float y = acc[t][r] + bv;
      y = (y >= 0.f) ? y : NEG_SLOPE * y;
      out[(size_t)row * COUT + n0 + l16] = y;
    }
  }
}

static inline size_t align_up(size_t v, size_t a) { return (v + a - 1) & ~(a - 1); }

extern "C" void kernel_launch(void* const* d_in, const int* in_sizes, int n_in,
                              void* d_out, int out_size, void* d_ws, size_t ws_size,
                              hipStream_t stream) {
  const float* x = (const float*)d_in[0];
  const int* edge_raw = (const int*)d_in[1];
  const float* W = (const float*)d_in[2];
  const float* b = (const float*)d_in[3];
  float* out = (float*)d_out;

  const int N = in_sizes[0] / CIN;
  const int E = in_sizes[1] / 2;
  const int NB = (N + 1023) / 1024;  // scan blocks (49 for N=50000, must be <=256)

  // Workspace layout
  char* w = (char*)d_ws;
  int* flag = (int*)w;            w += align_up(sizeof(int), 256);
  int* bsum = (int*)w;            w += align_up(256 * 4, 256);
  int* cnt = (int*)w;             w += align_up((size_t)N * 4, 256);
  int* rowptr = (int*)w;          w += align_up((size_t)N * 4, 256);
  int* cursor = (int*)w;          w += align_up((size_t)N * 4, 256);
  float* dinv = (float*)w;        w += align_up((size_t)N * 4, 256);
  int* srcA = (int*)w;            w += align_up((size_t)E * 4, 256);
  int* dstA = (int*)w;            w += align_up((size_t)E * 4, 256);
  int* col = (int*)w;             w += align_up((size_t)E * 4, 256);
  unsigned short* h2bf = (unsigned short*)w;  w += align_up((size_t)N * CIN * 2, 256);
  unsigned short* Wbf = (unsigned short*)w;   w += align_up((size_t)COUT * CIN * 2, 256);

  float* h1 = out;  // d_out as fp32 scratch for hop-1 result (N*128 <= out_size)

  hipMemsetAsync(cnt, 0, (size_t)N * sizeof(int), stream);

  detect_kernel<<<1, 64, 0, stream>>>(edge_raw, flag, E);
  decode_count_kernel<<<(E + 255) / 256, 256, 0, stream>>>(edge_raw, flag, srcA, dstA, cnt, E, N);
  dinv_kernel<<<(N + 255) / 256, 256, 0, stream>>>(cnt, dinv, N);
  scan1_kernel<<<NB, 256, 0, stream>>>(cnt, rowptr, bsum, N);
  scan2_kernel<<<1, 256, 0, stream>>>(bsum, NB);
  scan3_kernel<<<NB, 256, 0, stream>>>(rowptr, bsum, cursor, N);
  scatter_kernel<<<(E + 255) / 256, 256, 0, stream>>>(srcA, dstA, cursor, col, E);

  hop_kernel<false><<<N, 64, 0, stream>>>(x, dinv, rowptr, cnt, col, (void*)h1, N);
  hop_kernel<true><<<N, 64, 0, stream>>>(h1, dinv, rowptr, cnt, col, (void*)h2bf, N);

  wconv_kernel<<<(COUT * CIN + 255) / 256, 256, 0, stream>>>(W, Wbf, COUT * CIN);

  dim3 ggrid((N + 63) / 64, COUT / 64);
  gemm_kernel<<<ggrid, 256, 0, stream>>>(h2bf, Wbf, b, out, N);
}

// Round 3
// 375.732 us; speedup vs baseline: 1.6109x; 1.0752x over previous
//
#include <hip/hip_runtime.h>
#include <hip/hip_bf16.h>

#define CIN 128
#define COUT 512
#define NEG_SLOPE 0.1f

typedef __bf16 bf16x8 __attribute__((ext_vector_type(8)));
typedef float f32x4 __attribute__((ext_vector_type(4)));

static __device__ __forceinline__ unsigned short f2bf(float f) {
  unsigned int u = __builtin_bit_cast(unsigned int, f);
  unsigned int lsb = (u >> 16) & 1u;
  u += 0x7fffu + lsb;  // round-to-nearest-even
  return (unsigned short)(u >> 16);
}

// ---- Edge dtype probe: int64 stored data has every odd int32 word == 0 ----
__global__ void detect_kernel(const int* __restrict__ raw, int* __restrict__ flag, int E) {
  __shared__ int any_nonzero;
  int tid = threadIdx.x;  // 64 threads
  if (tid == 0) any_nonzero = 0;
  __syncthreads();
  int v1 = raw[2 * tid + 1];                  // odd words near start
  int v2 = raw[2 * (E / 2) + 2 * tid + 1];    // odd words near row-1 start
  if (v1 != 0 || v2 != 0) atomicOr(&any_nonzero, 1);
  __syncthreads();
  if (tid == 0) *flag = any_nonzero ? 0 : 1;  // 1 => data is int64
}

// Fused decode + degree count.
__global__ void decode_count_kernel(const int* __restrict__ raw, const int* __restrict__ flag,
                                    int* __restrict__ srcA, int* __restrict__ dstA,
                                    int* __restrict__ cnt, int E, int N) {
  int e = blockIdx.x * blockDim.x + threadIdx.x;
  if (e >= E) return;
  int is64 = *flag;
  int s, d;
  if (is64) {
    s = raw[2 * e];            // low word of element e (row 0)
    d = raw[2 * (E + e)];      // low word of element E+e (row 1)
  } else {
    s = raw[e];
    d = raw[E + e];
  }
  if ((unsigned)s >= (unsigned)N) s = 0;  // safety clamp
  if ((unsigned)d >= (unsigned)N) d = 0;
  srcA[e] = s;
  dstA[e] = d;
  atomicAdd(&cnt[d], 1);
}

__global__ void dinv_kernel(const int* __restrict__ cnt, float* __restrict__ dinv, int N) {
  int i = blockIdx.x * blockDim.x + threadIdx.x;
  if (i < N) dinv[i] = 1.0f / sqrtf((float)(cnt[i] + 1));  // +1 = self-loop
}

// ---- Hierarchical device-wide exclusive scan ----
__global__ __launch_bounds__(256) void scan1_kernel(const int* __restrict__ cnt,
                                                    int* __restrict__ rowptr,
                                                    int* __restrict__ bsum, int N) {
  __shared__ int buf[256];
  int tid = threadIdx.x;
  int base = blockIdx.x * 1024 + tid * 4;
  int v[4];
  int tot = 0;
#pragma unroll
  for (int k = 0; k < 4; ++k) {
    int i = base + k;
    v[k] = (i < N) ? cnt[i] : 0;
    tot += v[k];
  }
  buf[tid] = tot;
  __syncthreads();
  for (int off = 1; off < 256; off <<= 1) {
    int t = (tid >= off) ? buf[tid - off] : 0;
    __syncthreads();
    buf[tid] += t;
    __syncthreads();
  }
  int run = buf[tid] - tot;
  if (tid == 255) bsum[blockIdx.x] = buf[255];
#pragma unroll
  for (int k = 0; k < 4; ++k) {
    int i = base + k;
    if (i < N) rowptr[i] = run;
    run += v[k];
  }
}

__global__ void scan2_kernel(int* __restrict__ bsum, int nb) {
  __shared__ int buf[256];
  int tid = threadIdx.x;
  int v = (tid < nb) ? bsum[tid] : 0;
  buf[tid] = v;
  __syncthreads();
  for (int off = 1; off < 256; off <<= 1) {
    int t = (tid >= off) ? buf[tid - off] : 0;
    __syncthreads();
    buf[tid] += t;
    __syncthreads();
  }
  if (tid < nb) bsum[tid] = buf[tid] - v;
}

__global__ __launch_bounds__(256) void scan3_kernel(int* __restrict__ rowptr,
                                                    const int* __restrict__ bsum,
                                                    int* __restrict__ cursor, int N) {
  int base = blockIdx.x * 1024 + threadIdx.x * 4;
  int off = bsum[blockIdx.x];
#pragma unroll
  for (int k = 0; k < 4; ++k) {
    int i = base + k;
    if (i < N) {
      int r = rowptr[i] + off;
      rowptr[i] = r;
      cursor[i] = r;
    }
  }
}

__global__ void scatter_kernel(const int* __restrict__ srcA, const int* __restrict__ dstA,
                               int* __restrict__ cursor, int* __restrict__ col, int E) {
  int e = blockIdx.x * blockDim.x + threadIdx.x;
  if (e < E) {
    int pos = atomicAdd(&cursor[dstA[e]], 1);
    col[pos] = srcA[e];
  }
}

// Gather hop: 32 lanes per node (float4/lane covers 128 channels), 8 nodes
// per 256-thread block. OUT_BF16 selects fp32 (hop 1) vs bf16 (hop 2) output.
template <bool OUT_BF16>
__global__ __launch_bounds__(256) void hop_kernel(
    const float* __restrict__ X, const float* __restrict__ dinv,
    const int* __restrict__ rowptr, const int* __restrict__ cnt,
    const int* __restrict__ col, void* __restrict__ Yv, int N) {
  int sub = threadIdx.x & 31;
  int node = blockIdx.x * 8 + (threadIdx.x >> 5);
  if (node >= N) return;
  float di = dinv[node];
  int beg = rowptr[node];
  int num = cnt[node];
  float4 xv = ((const float4*)X + (size_t)node * 32)[sub];
  float s = di * di;
  float ax = s * xv.x, ay = s * xv.y, az = s * xv.z, aw = s * xv.w;
  int j = (num > 0) ? col[beg] : 0;
  for (int k = 0; k < num; ++k) {
    int jn = (k + 1 < num) ? col[beg + k + 1] : 0;  // prefetch next index
    float nrm = dinv[j] * di;
    float4 v = ((const float4*)X + (size_t)j * 32)[sub];
    ax += nrm * v.x;
    ay += nrm * v.y;
    az += nrm * v.z;
    aw += nrm * v.w;
    j = jn;
  }
  if constexpr (OUT_BF16) {
    ushort4 o;
    o.x = f2bf(ax); o.y = f2bf(ay); o.z = f2bf(az); o.w = f2bf(aw);
    ((ushort4*)Yv + (size_t)node * 32)[sub] = o;
  } else {
    float4 o;
    o.x = ax; o.y = ay; o.z = az; o.w = aw;
    ((float4*)Yv + (size_t)node * 32)[sub] = o;
  }
}

__global__ void wconv_kernel(const float* __restrict__ W, unsigned short* __restrict__ Wbf, int n) {
  int i = blockIdx.x * blockDim.x + threadIdx.x;
  if (i < n) Wbf[i] = f2bf(W[i]);
}

// y = h2 @ W^T + b, LeakyReLU. Block = 32 rows x full COUT=512.
// Wave w owns 128-col panel. A-frags preloaded once per wave (A fetched from
// HBM exactly once per block); W streamed from L2 (0.5 MB, resident).
__global__ __launch_bounds__(256) void gemm_kernel(
    const unsigned short* __restrict__ Abf, const unsigned short* __restrict__ Wbf,
    const float* __restrict__ bias, float* __restrict__ out, int M) {
  int wave = threadIdx.x >> 6;
  int lane = threadIdx.x & 63;
  int quad = lane >> 4;
  int l16 = lane & 15;
  int mbase = blockIdx.x * 32;

  bool valid1 = (mbase + 16) < M;  // M % 16 == 0: tile t fully valid iff start < M

  // Preload A fragments: A[m=l16][k=kk*32+quad*8+j], t in {0,1}
  bf16x8 af[2][4];
#pragma unroll
  for (int kk = 0; kk < 4; ++kk) {
    af[0][kk] = *(const bf16x8*)(Abf + (size_t)(mbase + l16) * CIN + kk * 32 + quad * 8);
    af[1][kk] = valid1
        ? *(const bf16x8*)(Abf + (size_t)(mbase + 16 + l16) * CIN + kk * 32 + quad * 8)
        : bf16x8{};
  }

  int nbase = wave * 128;
#pragma unroll
  for (int nt = 0; nt < 8; ++nt) {
    int n = nbase + nt * 16 + l16;
    const bf16x8* Wrow = (const bf16x8*)(Wbf + (size_t)n * CIN);
    f32x4 acc0 = {}, acc1 = {};
#pragma unroll
    for (int kk = 0; kk < 4; ++kk) {
      bf16x8 bfrag = Wrow[kk * 4 + quad];  // B[k=kk*32+quad*8+j][n]
      acc0 = __builtin_amdgcn_mfma_f32_16x16x32_bf16(af[0][kk], bfrag, acc0, 0, 0, 0);
      acc1 = __builtin_amdgcn_mfma_f32_16x16x32_bf16(af[1][kk], bfrag, acc1, 0, 0, 0);
    }
    float bv = bias[n];
#pragma unroll
    for (int r = 0; r < 4; ++r) {
      int row0 = mbase + quad * 4 + r;  // C/D: row=quad*4+r, col=l16
      float y0 = acc0[r] + bv;
      y0 = (y0 >= 0.f) ? y0 : NEG_SLOPE * y0;
      out[(size_t)row0 * COUT + n] = y0;
      if (valid1) {
        float y1 = acc1[r] + bv;
        y1 = (y1 >= 0.f) ? y1 : NEG_SLOPE * y1;
        out[(size_t)(row0 + 16) * COUT + n] = y1;
      }
    }
  }
}

static inline size_t align_up(size_t v, size_t a) { return (v + a - 1) & ~(a - 1); }

extern "C" void kernel_launch(void* const* d_in, const int* in_sizes, int n_in,
                              void* d_out, int out_size, void* d_ws, size_t ws_size,
                              hipStream_t stream) {
  const float* x = (const float*)d_in[0];
  const int* edge_raw = (const int*)d_in[1];
  const float* W = (const float*)d_in[2];
  const float* b = (const float*)d_in[3];
  float* out = (float*)d_out;

  const int N = in_sizes[0] / CIN;
  const int E = in_sizes[1] / 2;
  const int NB = (N + 1023) / 1024;  // scan blocks (49 for N=50000)

  // Workspace layout
  char* w = (char*)d_ws;
  int* flag = (int*)w;            w += align_up(sizeof(int), 256);
  int* bsum = (int*)w;            w += align_up(256 * 4, 256);
  int* cnt = (int*)w;             w += align_up((size_t)N * 4, 256);
  int* rowptr = (int*)w;          w += align_up((size_t)N * 4, 256);
  int* cursor = (int*)w;          w += align_up((size_t)N * 4, 256);
  float* dinv = (float*)w;        w += align_up((size_t)N * 4, 256);
  int* srcA = (int*)w;            w += align_up((size_t)E * 4, 256);
  int* dstA = (int*)w;            w += align_up((size_t)E * 4, 256);
  int* col = (int*)w;             w += align_up((size_t)E * 4, 256);
  unsigned short* h2bf = (unsigned short*)w;  w += align_up((size_t)N * CIN * 2, 256);
  unsigned short* Wbf = (unsigned short*)w;   w += align_up((size_t)COUT * CIN * 2, 256);

  float* h1 = out;  // d_out as fp32 scratch for hop-1 result

  hipMemsetAsync(cnt, 0, (size_t)N * sizeof(int), stream);

  detect_kernel<<<1, 64, 0, stream>>>(edge_raw, flag, E);
  decode_count_kernel<<<(E + 255) / 256, 256, 0, stream>>>(edge_raw, flag, srcA, dstA, cnt, E, N);
  dinv_kernel<<<(N + 255) / 256, 256, 0, stream>>>(cnt, dinv, N);
  scan1_kernel<<<NB, 256, 0, stream>>>(cnt, rowptr, bsum, N);
  scan2_kernel<<<1, 256, 0, stream>>>(bsum, NB);
  scan3_kernel<<<NB, 256, 0, stream>>>(rowptr, bsum, cursor, N);
  scatter_kernel<<<(E + 255) / 256, 256, 0, stream>>>(srcA, dstA, cursor, col, E);

  hop_kernel<false><<<(N + 7) / 8, 256, 0, stream>>>(x, dinv, rowptr, cnt, col, (void*)h1, N);
  hop_kernel<true><<<(N + 7) / 8, 256, 0, stream>>>(h1, dinv, rowptr, cnt, col, (void*)h2bf, N);

  wconv_kernel<<<(COUT * CIN + 255) / 256, 256, 0, stream>>>(W, Wbf, COUT * CIN);

  gemm_kernel<<<(N + 31) / 32, 256, 0, stream>>>(h2bf, Wbf, b, out, N);
}

// Round 4
// 329.649 us; speedup vs baseline: 1.8361x; 1.1398x over previous
//
#include <hip/hip_runtime.h>
#include <hip/hip_bf16.h>

#define CIN 128
#define COUT 512
#define NEG_SLOPE 0.1f

typedef __bf16 bf16x8 __attribute__((ext_vector_type(8)));
typedef float f32x4 __attribute__((ext_vector_type(4)));

static __device__ __forceinline__ unsigned short f2bf(float f) {
  unsigned int u = __builtin_bit_cast(unsigned int, f);
  unsigned int lsb = (u >> 16) & 1u;
  u += 0x7fffu + lsb;  // round-to-nearest-even
  return (unsigned short)(u >> 16);
}
static __device__ __forceinline__ float bf2f(unsigned short u) {
  unsigned int v = ((unsigned int)u) << 16;
  return __builtin_bit_cast(float, v);
}

// ---- Edge dtype probe: int64 stored data has every odd int32 word == 0 ----
__global__ void detect_kernel(const int* __restrict__ raw, int* __restrict__ flag, int E) {
  __shared__ int any_nonzero;
  int tid = threadIdx.x;  // 64 threads
  if (tid == 0) any_nonzero = 0;
  __syncthreads();
  int v1 = raw[2 * tid + 1];
  int v2 = raw[2 * (E / 2) + 2 * tid + 1];
  if (v1 != 0 || v2 != 0) atomicOr(&any_nonzero, 1);
  __syncthreads();
  if (tid == 0) *flag = any_nonzero ? 0 : 1;  // 1 => data is int64
}

// Fused decode + degree count.
__global__ void decode_count_kernel(const int* __restrict__ raw, const int* __restrict__ flag,
                                    int* __restrict__ srcA, int* __restrict__ dstA,
                                    int* __restrict__ cnt, int E, int N) {
  int e = blockIdx.x * blockDim.x + threadIdx.x;
  if (e >= E) return;
  int is64 = *flag;
  int s, d;
  if (is64) {
    s = raw[2 * e];
    d = raw[2 * (E + e)];
  } else {
    s = raw[e];
    d = raw[E + e];
  }
  if ((unsigned)s >= (unsigned)N) s = 0;
  if ((unsigned)d >= (unsigned)N) d = 0;
  srcA[e] = s;
  dstA[e] = d;
  atomicAdd(&cnt[d], 1);
}

__global__ void dinv_kernel(const int* __restrict__ cnt, float* __restrict__ dinv, int N) {
  int i = blockIdx.x * blockDim.x + threadIdx.x;
  if (i < N) dinv[i] = 1.0f / sqrtf((float)(cnt[i] + 1));  // +1 = self-loop
}

// xs[row] = dinv[row] * x[row], stored bf16 (256 B per row).
__global__ __launch_bounds__(256) void xscale_kernel(const float* __restrict__ x,
                                                     const float* __restrict__ dinv,
                                                     unsigned short* __restrict__ xs, int N) {
  int idx = blockIdx.x * blockDim.x + threadIdx.x;  // one float4 group
  if (idx >= N * (CIN / 4)) return;
  int row = idx >> 5;  // 32 float4 groups per row
  float d = dinv[row];
  float4 v = ((const float4*)x)[idx];
  ushort4 o;
  o.x = f2bf(v.x * d); o.y = f2bf(v.y * d); o.z = f2bf(v.z * d); o.w = f2bf(v.w * d);
  ((ushort4*)xs)[idx] = o;
}

// ---- Hierarchical device-wide exclusive scan ----
__global__ __launch_bounds__(256) void scan1_kernel(const int* __restrict__ cnt,
                                                    int* __restrict__ rowptr,
                                                    int* __restrict__ bsum, int N) {
  __shared__ int buf[256];
  int tid = threadIdx.x;
  int base = blockIdx.x * 1024 + tid * 4;
  int v[4];
  int tot = 0;
#pragma unroll
  for (int k = 0; k < 4; ++k) {
    int i = base + k;
    v[k] = (i < N) ? cnt[i] : 0;
    tot += v[k];
  }
  buf[tid] = tot;
  __syncthreads();
  for (int off = 1; off < 256; off <<= 1) {
    int t = (tid >= off) ? buf[tid - off] : 0;
    __syncthreads();
    buf[tid] += t;
    __syncthreads();
  }
  int run = buf[tid] - tot;
  if (tid == 255) bsum[blockIdx.x] = buf[255];
#pragma unroll
  for (int k = 0; k < 4; ++k) {
    int i = base + k;
    if (i < N) rowptr[i] = run;
    run += v[k];
  }
}

__global__ void scan2_kernel(int* __restrict__ bsum, int nb) {
  __shared__ int buf[256];
  int tid = threadIdx.x;
  int v = (tid < nb) ? bsum[tid] : 0;
  buf[tid] = v;
  __syncthreads();
  for (int off = 1; off < 256; off <<= 1) {
    int t = (tid >= off) ? buf[tid - off] : 0;
    __syncthreads();
    buf[tid] += t;
    __syncthreads();
  }
  if (tid < nb) bsum[tid] = buf[tid] - v;
}

__global__ __launch_bounds__(256) void scan3_kernel(int* __restrict__ rowptr,
                                                    const int* __restrict__ bsum,
                                                    int* __restrict__ cursor, int N) {
  int base = blockIdx.x * 1024 + threadIdx.x * 4;
  int off = bsum[blockIdx.x];
#pragma unroll
  for (int k = 0; k < 4; ++k) {
    int i = base + k;
    if (i < N) {
      int r = rowptr[i] + off;
      rowptr[i] = r;
      cursor[i] = r;
    }
  }
}

__global__ void scatter_kernel(const int* __restrict__ srcA, const int* __restrict__ dstA,
                               int* __restrict__ cursor, int* __restrict__ col, int E) {
  int e = blockIdx.x * blockDim.x + threadIdx.x;
  if (e < E) {
    int pos = atomicAdd(&cursor[dstA[e]], 1);
    col[pos] = srcA[e];
  }
}

// Gather hop over pre-scaled bf16 rows (256 B/row). 32 lanes per node
// (ushort4/lane), 8 nodes per 256-thread block, 2-way unrolled gather.
// Output: SQ ? di^2 * sum (h1s, feeds next hop's gather)
//            : di   * sum (h2, feeds GEMM).
template <bool SQ>
__global__ __launch_bounds__(256) void hop_kernel(
    const unsigned short* __restrict__ Xs, const float* __restrict__ dinv,
    const int* __restrict__ rowptr, const int* __restrict__ cnt,
    const int* __restrict__ col, unsigned short* __restrict__ Y, int N) {
  int sub = threadIdx.x & 31;
  int node = blockIdx.x * 8 + (threadIdx.x >> 5);
  if (node >= N) return;
  int beg = rowptr[node];
  int num = cnt[node];
  const ushort4* X4 = (const ushort4*)Xs;
  ushort4 self = X4[(size_t)node * 32 + sub];
  float ax = bf2f(self.x), ay = bf2f(self.y), az = bf2f(self.z), aw = bf2f(self.w);
  float bx = 0.f, by = 0.f, bz = 0.f, bw = 0.f;
  int k = 0;
  for (; k + 2 <= num; k += 2) {
    int j0 = col[beg + k];
    int j1 = col[beg + k + 1];
    ushort4 v0 = X4[(size_t)j0 * 32 + sub];
    ushort4 v1 = X4[(size_t)j1 * 32 + sub];
    ax += bf2f(v0.x); ay += bf2f(v0.y); az += bf2f(v0.z); aw += bf2f(v0.w);
    bx += bf2f(v1.x); by += bf2f(v1.y); bz += bf2f(v1.z); bw += bf2f(v1.w);
  }
  if (k < num) {
    int j0 = col[beg + k];
    ushort4 v0 = X4[(size_t)j0 * 32 + sub];
    ax += bf2f(v0.x); ay += bf2f(v0.y); az += bf2f(v0.z); aw += bf2f(v0.w);
  }
  float di = dinv[node];
  float sc = SQ ? di * di : di;
  ushort4 o;
  o.x = f2bf((ax + bx) * sc);
  o.y = f2bf((ay + by) * sc);
  o.z = f2bf((az + bz) * sc);
  o.w = f2bf((aw + bw) * sc);
  ((ushort4*)Y)[(size_t)node * 32 + sub] = o;
}

__global__ void wconv_kernel(const float* __restrict__ W, unsigned short* __restrict__ Wbf, int n) {
  int i = blockIdx.x * blockDim.x + threadIdx.x;
  if (i < n) Wbf[i] = f2bf(W[i]);
}

// y = h2 @ W^T + b, LeakyReLU. Block = 32 rows x full COUT=512.
__global__ __launch_bounds__(256) void gemm_kernel(
    const unsigned short* __restrict__ Abf, const unsigned short* __restrict__ Wbf,
    const float* __restrict__ bias, float* __restrict__ out, int M) {
  int wave = threadIdx.x >> 6;
  int lane = threadIdx.x & 63;
  int quad = lane >> 4;
  int l16 = lane & 15;
  int mbase = blockIdx.x * 32;

  bool valid1 = (mbase + 16) < M;

  bf16x8 af[2][4];
#pragma unroll
  for (int kk = 0; kk < 4; ++kk) {
    af[0][kk] = *(const bf16x8*)(Abf + (size_t)(mbase + l16) * CIN + kk * 32 + quad * 8);
    af[1][kk] = valid1
        ? *(const bf16x8*)(Abf + (size_t)(mbase + 16 + l16) * CIN + kk * 32 + quad * 8)
        : bf16x8{};
  }

  int nbase = wave * 128;
#pragma unroll
  for (int nt = 0; nt < 8; ++nt) {
    int n = nbase + nt * 16 + l16;
    const bf16x8* Wrow = (const bf16x8*)(Wbf + (size_t)n * CIN);
    f32x4 acc0 = {}, acc1 = {};
#pragma unroll
    for (int kk = 0; kk < 4; ++kk) {
      bf16x8 bfrag = Wrow[kk * 4 + quad];
      acc0 = __builtin_amdgcn_mfma_f32_16x16x32_bf16(af[0][kk], bfrag, acc0, 0, 0, 0);
      acc1 = __builtin_amdgcn_mfma_f32_16x16x32_bf16(af[1][kk], bfrag, acc1, 0, 0, 0);
    }
    float bv = bias[n];
#pragma unroll
    for (int r = 0; r < 4; ++r) {
      int row0 = mbase + quad * 4 + r;
      float y0 = acc0[r] + bv;
      y0 = (y0 >= 0.f) ? y0 : NEG_SLOPE * y0;
      out[(size_t)row0 * COUT + n] = y0;
      if (valid1) {
        float y1 = acc1[r] + bv;
        y1 = (y1 >= 0.f) ? y1 : NEG_SLOPE * y1;
        out[(size_t)(row0 + 16) * COUT + n] = y1;
      }
    }
  }
}

static inline size_t align_up(size_t v, size_t a) { return (v + a - 1) & ~(a - 1); }

extern "C" void kernel_launch(void* const* d_in, const int* in_sizes, int n_in,
                              void* d_out, int out_size, void* d_ws, size_t ws_size,
                              hipStream_t stream) {
  const float* x = (const float*)d_in[0];
  const int* edge_raw = (const int*)d_in[1];
  const float* W = (const float*)d_in[2];
  const float* b = (const float*)d_in[3];
  float* out = (float*)d_out;

  const int N = in_sizes[0] / CIN;
  const int E = in_sizes[1] / 2;
  const int NB = (N + 1023) / 1024;  // scan blocks (49 for N=50000)

  // Workspace layout
  char* w = (char*)d_ws;
  int* flag = (int*)w;            w += align_up(sizeof(int), 256);
  int* bsum = (int*)w;            w += align_up(256 * 4, 256);
  int* cnt = (int*)w;             w += align_up((size_t)N * 4, 256);
  int* rowptr = (int*)w;          w += align_up((size_t)N * 4, 256);
  int* cursor = (int*)w;          w += align_up((size_t)N * 4, 256);
  float* dinv = (float*)w;        w += align_up((size_t)N * 4, 256);
  int* srcA = (int*)w;            w += align_up((size_t)E * 4, 256);
  int* dstA = (int*)w;            w += align_up((size_t)E * 4, 256);
  int* col = (int*)w;             w += align_up((size_t)E * 4, 256);
  unsigned short* h2bf = (unsigned short*)w;  w += align_up((size_t)N * CIN * 2, 256);
  unsigned short* Wbf = (unsigned short*)w;   w += align_up((size_t)COUT * CIN * 2, 256);

  // bf16 row buffers live in the tail of d_out (scratch until GEMM's final
  // write): xs = dinv-scaled x; h1s = dinv-scaled hop-1 output.
  size_t outb = (size_t)out_size * sizeof(float);
  size_t rowb = (size_t)N * CIN * sizeof(unsigned short);
  unsigned short* h1s = (unsigned short*)((char*)d_out + (outb - rowb));
  unsigned short* xs = (unsigned short*)((char*)d_out + (outb - 2 * rowb));

  hipMemsetAsync(cnt, 0, (size_t)N * sizeof(int), stream);

  detect_kernel<<<1, 64, 0, stream>>>(edge_raw, flag, E);
  decode_count_kernel<<<(E + 255) / 256, 256, 0, stream>>>(edge_raw, flag, srcA, dstA, cnt, E, N);
  dinv_kernel<<<(N + 255) / 256, 256, 0, stream>>>(cnt, dinv, N);
  scan1_kernel<<<NB, 256, 0, stream>>>(cnt, rowptr, bsum, N);
  scan2_kernel<<<1, 256, 0, stream>>>(bsum, NB);
  scan3_kernel<<<NB, 256, 0, stream>>>(rowptr, bsum, cursor, N);
  scatter_kernel<<<(E + 255) / 256, 256, 0, stream>>>(srcA, dstA, cursor, col, E);
  xscale_kernel<<<(N * (CIN / 4) + 255) / 256, 256, 0, stream>>>(x, dinv, xs, N);

  hop_kernel<true><<<(N + 7) / 8, 256, 0, stream>>>(xs, dinv, rowptr, cnt, col, h1s, N);
  hop_kernel<false><<<(N + 7) / 8, 256, 0, stream>>>(h1s, dinv, rowptr, cnt, col, h2bf, N);

  wconv_kernel<<<(COUT * CIN + 255) / 256, 256, 0, stream>>>(W, Wbf, COUT * CIN);

  gemm_kernel<<<(N + 31) / 32, 256, 0, stream>>>(h2bf, Wbf, b, out, N);
}

// Round 5
// 311.318 us; speedup vs baseline: 1.9442x; 1.0589x over previous
//
#include <hip/hip_runtime.h>
#include <hip/hip_bf16.h>

#define CIN 128
#define COUT 512
#define NEG_SLOPE 0.1f

typedef __bf16 bf16x8 __attribute__((ext_vector_type(8)));
typedef float f32x4 __attribute__((ext_vector_type(4)));

static __device__ __forceinline__ unsigned short f2bf(float f) {
  unsigned int u = __builtin_bit_cast(unsigned int, f);
  unsigned int lsb = (u >> 16) & 1u;
  u += 0x7fffu + lsb;  // round-to-nearest-even
  return (unsigned short)(u >> 16);
}
static __device__ __forceinline__ float bf_lo(unsigned int u) {
  return __builtin_bit_cast(float, u << 16);
}
static __device__ __forceinline__ float bf_hi(unsigned int u) {
  return __builtin_bit_cast(float, u & 0xffff0000u);
}
static __device__ __forceinline__ unsigned int pack2(float lo, float hi) {
  return (unsigned int)f2bf(lo) | ((unsigned int)f2bf(hi) << 16);
}

// ---- Edge dtype probe: int64 stored data has every odd int32 word == 0 ----
__global__ void detect_kernel(const int* __restrict__ raw, int* __restrict__ flag, int E) {
  __shared__ int any_nonzero;
  int tid = threadIdx.x;  // 64 threads
  if (tid == 0) any_nonzero = 0;
  __syncthreads();
  int v1 = raw[2 * tid + 1];
  int v2 = raw[2 * (E / 2) + 2 * tid + 1];
  if (v1 != 0 || v2 != 0) atomicOr(&any_nonzero, 1);
  __syncthreads();
  if (tid == 0) *flag = any_nonzero ? 0 : 1;  // 1 => data is int64
}

// Fused decode + degree count.
__global__ void decode_count_kernel(const int* __restrict__ raw, const int* __restrict__ flag,
                                    int* __restrict__ srcA, int* __restrict__ dstA,
                                    int* __restrict__ cnt, int E, int N) {
  int e = blockIdx.x * blockDim.x + threadIdx.x;
  if (e >= E) return;
  int is64 = *flag;
  int s, d;
  if (is64) {
    s = raw[2 * e];
    d = raw[2 * (E + e)];
  } else {
    s = raw[e];
    d = raw[E + e];
  }
  if ((unsigned)s >= (unsigned)N) s = 0;
  if ((unsigned)d >= (unsigned)N) d = 0;
  srcA[e] = s;
  dstA[e] = d;
  atomicAdd(&cnt[d], 1);
}

__global__ void dinv_kernel(const int* __restrict__ cnt, float* __restrict__ dinv, int N) {
  int i = blockIdx.x * blockDim.x + threadIdx.x;
  if (i < N) dinv[i] = 1.0f / sqrtf((float)(cnt[i] + 1));  // +1 = self-loop
}

// xs[row] = dinv[row] * x[row], stored bf16 (256 B per row).
__global__ __launch_bounds__(256) void xscale_kernel(const float* __restrict__ x,
                                                     const float* __restrict__ dinv,
                                                     unsigned short* __restrict__ xs, int N) {
  int idx = blockIdx.x * blockDim.x + threadIdx.x;  // one float4 group
  if (idx >= N * (CIN / 4)) return;
  int row = idx >> 5;  // 32 float4 groups per row
  float d = dinv[row];
  float4 v = ((const float4*)x)[idx];
  ushort4 o;
  o.x = f2bf(v.x * d); o.y = f2bf(v.y * d); o.z = f2bf(v.z * d); o.w = f2bf(v.w * d);
  ((ushort4*)xs)[idx] = o;
}

// ---- Hierarchical device-wide exclusive scan ----
__global__ __launch_bounds__(256) void scan1_kernel(const int* __restrict__ cnt,
                                                    int* __restrict__ rowptr,
                                                    int* __restrict__ bsum, int N) {
  __shared__ int buf[256];
  int tid = threadIdx.x;
  int base = blockIdx.x * 1024 + tid * 4;
  int v[4];
  int tot = 0;
#pragma unroll
  for (int k = 0; k < 4; ++k) {
    int i = base + k;
    v[k] = (i < N) ? cnt[i] : 0;
    tot += v[k];
  }
  buf[tid] = tot;
  __syncthreads();
  for (int off = 1; off < 256; off <<= 1) {
    int t = (tid >= off) ? buf[tid - off] : 0;
    __syncthreads();
    buf[tid] += t;
    __syncthreads();
  }
  int run = buf[tid] - tot;
  if (tid == 255) bsum[blockIdx.x] = buf[255];
#pragma unroll
  for (int k = 0; k < 4; ++k) {
    int i = base + k;
    if (i < N) rowptr[i] = run;
    run += v[k];
  }
}

__global__ void scan2_kernel(int* __restrict__ bsum, int nb) {
  __shared__ int buf[256];
  int tid = threadIdx.x;
  int v = (tid < nb) ? bsum[tid] : 0;
  buf[tid] = v;
  __syncthreads();
  for (int off = 1; off < 256; off <<= 1) {
    int t = (tid >= off) ? buf[tid - off] : 0;
    __syncthreads();
    buf[tid] += t;
    __syncthreads();
  }
  if (tid < nb) bsum[tid] = buf[tid] - v;
}

__global__ __launch_bounds__(256) void scan3_kernel(int* __restrict__ rowptr,
                                                    const int* __restrict__ bsum,
                                                    int* __restrict__ cursor, int N) {
  int base = blockIdx.x * 1024 + threadIdx.x * 4;
  int off = bsum[blockIdx.x];
#pragma unroll
  for (int k = 0; k < 4; ++k) {
    int i = base + k;
    if (i < N) {
      int r = rowptr[i] + off;
      rowptr[i] = r;
      cursor[i] = r;
    }
  }
}

__global__ void scatter_kernel(const int* __restrict__ srcA, const int* __restrict__ dstA,
                               int* __restrict__ cursor, int* __restrict__ col, int E) {
  int e = blockIdx.x * blockDim.x + threadIdx.x;
  if (e < E) {
    int pos = atomicAdd(&cursor[dstA[e]], 1);
    col[pos] = srcA[e];
  }
}

// Gather hop over pre-scaled bf16 rows (256 B/row). 16 lanes per node
// (uint4 = 16 B/lane), 16 nodes per 256-thread block, 4-way unrolled gather
// (16 outstanding row loads per wave for MLP).
// Output: SQ ? di^2 * sum (h1s, feeds next hop) : di * sum (h2, feeds GEMM).
template <bool SQ>
__global__ __launch_bounds__(256) void hop_kernel(
    const unsigned short* __restrict__ Xs, const float* __restrict__ dinv,
    const int* __restrict__ rowptr, const int* __restrict__ cnt,
    const int* __restrict__ col, unsigned short* __restrict__ Y, int N) {
  int sub = threadIdx.x & 15;
  int node = blockIdx.x * 16 + (threadIdx.x >> 4);
  if (node >= N) return;
  int beg = rowptr[node];
  int num = cnt[node];
  const uint4* X4 = (const uint4*)Xs;  // one row = 16 uint4
  uint4 self = X4[(size_t)node * 16 + sub];
  float acc[8];
  acc[0] = bf_lo(self.x); acc[1] = bf_hi(self.x);
  acc[2] = bf_lo(self.y); acc[3] = bf_hi(self.y);
  acc[4] = bf_lo(self.z); acc[5] = bf_hi(self.z);
  acc[6] = bf_lo(self.w); acc[7] = bf_hi(self.w);
  int k = 0;
  for (; k + 4 <= num; k += 4) {
    int j0 = col[beg + k];
    int j1 = col[beg + k + 1];
    int j2 = col[beg + k + 2];
    int j3 = col[beg + k + 3];
    uint4 v0 = X4[(size_t)j0 * 16 + sub];
    uint4 v1 = X4[(size_t)j1 * 16 + sub];
    uint4 v2 = X4[(size_t)j2 * 16 + sub];
    uint4 v3 = X4[(size_t)j3 * 16 + sub];
    acc[0] += bf_lo(v0.x); acc[1] += bf_hi(v0.x);
    acc[2] += bf_lo(v0.y); acc[3] += bf_hi(v0.y);
    acc[4] += bf_lo(v0.z); acc[5] += bf_hi(v0.z);
    acc[6] += bf_lo(v0.w); acc[7] += bf_hi(v0.w);
    acc[0] += bf_lo(v1.x); acc[1] += bf_hi(v1.x);
    acc[2] += bf_lo(v1.y); acc[3] += bf_hi(v1.y);
    acc[4] += bf_lo(v1.z); acc[5] += bf_hi(v1.z);
    acc[6] += bf_lo(v1.w); acc[7] += bf_hi(v1.w);
    acc[0] += bf_lo(v2.x); acc[1] += bf_hi(v2.x);
    acc[2] += bf_lo(v2.y); acc[3] += bf_hi(v2.y);
    acc[4] += bf_lo(v2.z); acc[5] += bf_hi(v2.z);
    acc[6] += bf_lo(v2.w); acc[7] += bf_hi(v2.w);
    acc[0] += bf_lo(v3.x); acc[1] += bf_hi(v3.x);
    acc[2] += bf_lo(v3.y); acc[3] += bf_hi(v3.y);
    acc[4] += bf_lo(v3.z); acc[5] += bf_hi(v3.z);
    acc[6] += bf_lo(v3.w); acc[7] += bf_hi(v3.w);
  }
  for (; k < num; ++k) {
    int j0 = col[beg + k];
    uint4 v0 = X4[(size_t)j0 * 16 + sub];
    acc[0] += bf_lo(v0.x); acc[1] += bf_hi(v0.x);
    acc[2] += bf_lo(v0.y); acc[3] += bf_hi(v0.y);
    acc[4] += bf_lo(v0.z); acc[5] += bf_hi(v0.z);
    acc[6] += bf_lo(v0.w); acc[7] += bf_hi(v0.w);
  }
  float di = dinv[node];
  float sc = SQ ? di * di : di;
  uint4 o;
  o.x = pack2(acc[0] * sc, acc[1] * sc);
  o.y = pack2(acc[2] * sc, acc[3] * sc);
  o.z = pack2(acc[4] * sc, acc[5] * sc);
  o.w = pack2(acc[6] * sc, acc[7] * sc);
  ((uint4*)Y)[(size_t)node * 16 + sub] = o;
}

__global__ void wconv_kernel(const float* __restrict__ W, unsigned short* __restrict__ Wbf, int n) {
  int i = blockIdx.x * blockDim.x + threadIdx.x;
  if (i < n) Wbf[i] = f2bf(W[i]);
}

// y = h2 @ W^T + b, LeakyReLU. Block = 32 rows x full COUT=512.
__global__ __launch_bounds__(256) void gemm_kernel(
    const unsigned short* __restrict__ Abf, const unsigned short* __restrict__ Wbf,
    const float* __restrict__ bias, float* __restrict__ out, int M) {
  int wave = threadIdx.x >> 6;
  int lane = threadIdx.x & 63;
  int quad = lane >> 4;
  int l16 = lane & 15;
  int mbase = blockIdx.x * 32;

  bool valid1 = (mbase + 16) < M;

  bf16x8 af[2][4];
#pragma unroll
  for (int kk = 0; kk < 4; ++kk) {
    af[0][kk] = *(const bf16x8*)(Abf + (size_t)(mbase + l16) * CIN + kk * 32 + quad * 8);
    af[1][kk] = valid1
        ? *(const bf16x8*)(Abf + (size_t)(mbase + 16 + l16) * CIN + kk * 32 + quad * 8)
        : bf16x8{};
  }

  int nbase = wave * 128;
#pragma unroll
  for (int nt = 0; nt < 8; ++nt) {
    int n = nbase + nt * 16 + l16;
    const bf16x8* Wrow = (const bf16x8*)(Wbf + (size_t)n * CIN);
    f32x4 acc0 = {}, acc1 = {};
#pragma unroll
    for (int kk = 0; kk < 4; ++kk) {
      bf16x8 bfrag = Wrow[kk * 4 + quad];
      acc0 = __builtin_amdgcn_mfma_f32_16x16x32_bf16(af[0][kk], bfrag, acc0, 0, 0, 0);
      acc1 = __builtin_amdgcn_mfma_f32_16x16x32_bf16(af[1][kk], bfrag, acc1, 0, 0, 0);
    }
    float bv = bias[n];
#pragma unroll
    for (int r = 0; r < 4; ++r) {
      int row0 = mbase + quad * 4 + r;
      float y0 = acc0[r] + bv;
      y0 = (y0 >= 0.f) ? y0 : NEG_SLOPE * y0;
      out[(size_t)row0 * COUT + n] = y0;
      if (valid1) {
        float y1 = acc1[r] + bv;
        y1 = (y1 >= 0.f) ? y1 : NEG_SLOPE * y1;
        out[(size_t)(row0 + 16) * COUT + n] = y1;
      }
    }
  }
}

static inline size_t align_up(size_t v, size_t a) { return (v + a - 1) & ~(a - 1); }

extern "C" void kernel_launch(void* const* d_in, const int* in_sizes, int n_in,
                              void* d_out, int out_size, void* d_ws, size_t ws_size,
                              hipStream_t stream) {
  const float* x = (const float*)d_in[0];
  const int* edge_raw = (const int*)d_in[1];
  const float* W = (const float*)d_in[2];
  const float* b = (const float*)d_in[3];
  float* out = (float*)d_out;

  const int N = in_sizes[0] / CIN;
  const int E = in_sizes[1] / 2;
  const int NB = (N + 1023) / 1024;  // scan blocks (49 for N=50000)

  // Workspace layout
  char* w = (char*)d_ws;
  int* flag = (int*)w;            w += align_up(sizeof(int), 256);
  int* bsum = (int*)w;            w += align_up(256 * 4, 256);
  int* cnt = (int*)w;             w += align_up((size_t)N * 4, 256);
  int* rowptr = (int*)w;          w += align_up((size_t)N * 4, 256);
  int* cursor = (int*)w;          w += align_up((size_t)N * 4, 256);
  float* dinv = (float*)w;        w += align_up((size_t)N * 4, 256);
  int* srcA = (int*)w;            w += align_up((size_t)E * 4, 256);
  int* dstA = (int*)w;            w += align_up((size_t)E * 4, 256);
  int* col = (int*)w;             w += align_up((size_t)E * 4, 256);
  unsigned short* h2bf = (unsigned short*)w;  w += align_up((size_t)N * CIN * 2, 256);
  unsigned short* Wbf = (unsigned short*)w;   w += align_up((size_t)COUT * CIN * 2, 256);

  // bf16 row buffers in the tail of d_out (scratch until GEMM's final write).
  size_t outb = (size_t)out_size * sizeof(float);
  size_t rowb = (size_t)N * CIN * sizeof(unsigned short);
  unsigned short* h1s = (unsigned short*)((char*)d_out + (outb - rowb));
  unsigned short* xs = (unsigned short*)((char*)d_out + (outb - 2 * rowb));

  hipMemsetAsync(cnt, 0, (size_t)N * sizeof(int), stream);

  detect_kernel<<<1, 64, 0, stream>>>(edge_raw, flag, E);
  decode_count_kernel<<<(E + 255) / 256, 256, 0, stream>>>(edge_raw, flag, srcA, dstA, cnt, E, N);
  dinv_kernel<<<(N + 255) / 256, 256, 0, stream>>>(cnt, dinv, N);
  scan1_kernel<<<NB, 256, 0, stream>>>(cnt, rowptr, bsum, N);
  scan2_kernel<<<1, 256, 0, stream>>>(bsum, NB);
  scan3_kernel<<<NB, 256, 0, stream>>>(rowptr, bsum, cursor, N);
  scatter_kernel<<<(E + 255) / 256, 256, 0, stream>>>(srcA, dstA, cursor, col, E);
  xscale_kernel<<<(N * (CIN / 4) + 255) / 256, 256, 0, stream>>>(x, dinv, xs, N);

  hop_kernel<true><<<(N + 15) / 16, 256, 0, stream>>>(xs, dinv, rowptr, cnt, col, h1s, N);
  hop_kernel<false><<<(N + 15) / 16, 256, 0, stream>>>(h1s, dinv, rowptr, cnt, col, h2bf, N);

  wconv_kernel<<<(COUT * CIN + 255) / 256, 256, 0, stream>>>(W, Wbf, COUT * CIN);

  gemm_kernel<<<(N + 31) / 32, 256, 0, stream>>>(h2bf, Wbf, b, out, N);
}